// Round 7
// baseline (994.703 us; speedup 1.0000x reference)
//
#include <hip/hip_runtime.h>
#include <hip/hip_bf16.h>

constexpr int Bn  = 8;
constexpr int Np  = 2048;
constexpr int KNN = 32;

typedef __attribute__((ext_vector_type(8))) short bf16x8;
typedef __attribute__((ext_vector_type(4))) float f32x4;

__device__ static inline void gll16(const void* g, void* l) {
  __builtin_amdgcn_global_load_lds((const __attribute__((address_space(1))) void*)g,
                                   (__attribute__((address_space(3))) void*)l, 16, 0, 0);
}

__device__ static inline unsigned short f2bf(float x) {
  union { __hip_bfloat16 h; unsigned short u; } cv; cv.h = __float2bfloat16(x); return cv.u;
}
__device__ static inline float bf2f(unsigned short u) {
  union { __hip_bfloat16 h; unsigned short u; } cv; cv.u = u; return __bfloat162float(cv.h);
}

// ------------------------------------------------------------- helpers ----
__global__ __launch_bounds__(256)
void cvt_bf16_kernel(const float* __restrict__ s, __hip_bfloat16* __restrict__ d, int n) {
  int i = blockIdx.x * 256 + threadIdx.x;
  if (i < n) d[i] = __float2bfloat16(s[i]);
}

// W1a (first CIN cols of w1), zero-padded to K1, bf16.
template<int CIN, int K1>
__global__ __launch_bounds__(256)
void cvt_w1a(const float* __restrict__ w1, __hip_bfloat16* __restrict__ out) {
  int i = blockIdx.x * 256 + threadIdx.x;
  if (i >= 64 * K1) return;
  int o = i / K1, c = i - o * K1;
  out[i] = __float2bfloat16(c < CIN ? w1[o * 2 * CIN + c] : 0.f);
}

__global__ __launch_bounds__(256)
void xpose_kernel(const float* __restrict__ x, float* __restrict__ xt,
                  __hip_bfloat16* __restrict__ xb) {
  int i = blockIdx.x * 256 + threadIdx.x;   // over B*N
  int b = i >> 11, n = i & 2047;
  const float* p = x + (long)b * 3 * Np + n;
  float vx = p[0], vy = p[Np], vz = p[2 * Np];
  xt[(long)i * 4 + 0] = vx;
  xt[(long)i * 4 + 1] = vy;
  xt[(long)i * 4 + 2] = vz;
  xt[(long)i * 4 + 3] = 0.f;
  __hip_bfloat16* q = xb + (long)i * 8;
  q[0] = __float2bfloat16(vx); q[1] = __float2bfloat16(vy);
  q[2] = __float2bfloat16(vz);
  q[3] = __float2bfloat16(0.f); q[4] = q[3]; q[5] = q[3]; q[6] = q[3]; q[7] = q[3];
}

template<int C, int CP>
__global__ __launch_bounds__(256)
void sq_kernel(const float* __restrict__ f, float* __restrict__ out) {
  int i = blockIdx.x * 256 + threadIdx.x;   // over B*N
  const float* p = f + (long)i * CP;
  float s = 0.f;
#pragma unroll
  for (int c = 0; c < C; ++c) s += p[c] * p[c];
  out[i] = s;
}

// split fp32 feature -> hi/lo bf16 pair (for fp32-grade MFMA dot products)
template<int CIN, int CP>
__global__ __launch_bounds__(256)
void split_kernel(const float* __restrict__ f, __hip_bfloat16* __restrict__ fhi,
                  __hip_bfloat16* __restrict__ flo) {
  int i = blockIdx.x * 256 + threadIdx.x;   // over B*N*64
  int n = i >> 6, c = i & 63;
  float v = (c < CIN) ? f[(long)n * CP + c] : 0.f;
  __hip_bfloat16 h = __float2bfloat16(v);
  fhi[i] = h;
  flo[i] = __float2bfloat16(v - __bfloat162float(h));
}

// ------------------------------------------------------ topk machinery ----
__device__ static inline unsigned umin32(unsigned a, unsigned b) { return a < b ? a : b; }

__device__ static inline int mbcnt64(unsigned long long m) {
  return __builtin_amdgcn_mbcnt_hi((unsigned)(m >> 32),
         __builtin_amdgcn_mbcnt_lo((unsigned)m, 0u));
}

__device__ static inline unsigned long long shfl64x(unsigned long long k, int m) {
  unsigned lo = (unsigned)__shfl_xor((int)(unsigned)k, m);
  unsigned hi = (unsigned)__shfl_xor((int)(unsigned)(k >> 32), m);
  return ((unsigned long long)hi << 32) | (unsigned long long)lo;
}

// sort-based helpers retained ONLY for the (pathological) S>CAP fallback
__device__ static inline unsigned long long lane_sort64_u64(unsigned long long v, int lane) {
#pragma unroll
  for (int k = 2; k <= 64; k <<= 1) {
#pragma unroll
    for (int j = k >> 1; j > 0; j >>= 1) {
      unsigned long long o = shfl64x(v, j);
      bool dir = ((lane & k) == 0);
      bool lower = ((lane & j) == 0);
      bool keep = (v < o) == (dir == lower);
      v = keep ? v : o;
    }
  }
  return v;
}

__device__ static inline unsigned long long lane_merge64(unsigned long long a,
                                                         unsigned long long b, int lane) {
  unsigned long long br = shfl64x(b, 63);           // reverse of b
  unsigned long long m = a < br ? a : br;           // bitonic, holds lowest 64
#pragma unroll
  for (int j = 32; j > 0; j >>= 1) {
    unsigned long long o = shfl64x(m, j);
    bool lower = ((lane & j) == 0);
    bool keep = (m < o) == lower;
    m = keep ? m : o;
  }
  return m;
}

// k-th smallest (k = km1+1) of the 64 per-lane u32 values v, via bitwise
// binary search on the value domain.  Ballot-only, no DS-pipe shuffles.
__device__ static inline unsigned kth_u32(unsigned v, int km1) {
  unsigned p = 0;
#pragma unroll
  for (int b = 31; b >= 0; --b) {
    unsigned t = p | (1u << b);
    if ((int)__popcll(__ballot(v < t)) <= km1) p = t;
  }
  return p;
}

// Wave-level exact top-32 (by (val,idx) ascending key) of 2048 values held
// as val[32] per lane.  Output UNSORTED (consumer max-pools -> order-free);
// the selected SET is exactly the 32 smallest keys (ties by lowest index).
// MAP 0: idx = (s>>2)*256 + lane*4 + (s&3)   (float4-per-lane fill)
// MAP 1: idx = (s>>2)*256 + (s&3)*64 + lane  (lane-contiguous fill)
template<int MAP, int CAP>
__device__ static inline void row_topk(const unsigned* val, unsigned long long* cbuf,
                                       int lane, int* outp) {
  unsigned tmn[16];
#pragma unroll
  for (int i = 0; i < 16; ++i) tmn[i] = umin32(val[i], val[i + 16]);
#pragma unroll
  for (int w2 = 8; w2 >= 1; w2 >>= 1)
#pragma unroll
    for (int i = 0; i < 8; ++i)
      if (i < w2) tmn[i] = umin32(tmn[i], tmn[i + w2]);

  // T = 32nd smallest of the 64 lane-minima -> exact top-32 all survive v<=T
  unsigned T = kth_u32(tmn[0], 31);

  // ballot-compact survivors into cbuf
  int S = 0;
#pragma unroll
  for (int s = 0; s < 32; ++s) {
    bool p = val[s] <= T;
    unsigned long long mask = __ballot(p);
    int pos = S + mbcnt64(mask);
    unsigned idx = (MAP == 0) ? (unsigned)((s >> 2) * 256 + lane * 4 + (s & 3))
                              : (unsigned)((s >> 2) * 256 + (s & 3) * 64 + lane);
    if (p && pos < CAP) cbuf[pos] = ((unsigned long long)val[s] << 32) | idx;
    S += (int)__popcll(mask);
  }

  if (S <= 64) {
    // hot path: one survivor key per lane
    unsigned long long k = (lane < S) ? cbuf[lane] : ~0ull;
    unsigned vs = (unsigned)(k >> 32), ix = (unsigned)k;
    unsigned vstar = kth_u32(vs, 31);
    int c1 = (int)__popcll(__ballot(vs < vstar));
    int r = 32 - c1;                               // >= 1
    unsigned istar = 0;
#pragma unroll
    for (int b = 10; b >= 0; --b) {
      unsigned t = istar | (1u << b);
      if ((int)__popcll(__ballot(vs == vstar && ix < t)) <= r - 1) istar = t;
    }
    bool sel = (vs < vstar) || (vs == vstar && ix <= istar);
    unsigned long long m = __ballot(sel);
    if (sel) outp[mbcnt64(m)] = (int)ix;
  } else if (S <= CAP) {
    int nslot = (S + 63) >> 6;                     // 2..CAP/64, wave-uniform
    unsigned vs[CAP / 64], is_[CAP / 64];
#pragma unroll
    for (int q = 0; q < CAP / 64; ++q) {
      unsigned long long k = (q * 64 + lane < S) ? cbuf[q * 64 + lane] : ~0ull;
      vs[q] = (unsigned)(k >> 32);
      is_[q] = (unsigned)k;
    }
    unsigned vstar = 0;
#pragma unroll
    for (int b = 31; b >= 0; --b) {
      unsigned t = vstar | (1u << b);
      int c = 0;
      for (int q = 0; q < nslot; ++q) c += (int)__popcll(__ballot(vs[q] < t));
      if (c <= 31) vstar = t;
    }
    int c1 = 0;
    for (int q = 0; q < nslot; ++q) c1 += (int)__popcll(__ballot(vs[q] < vstar));
    int r = 32 - c1;
    unsigned istar = 0;
#pragma unroll
    for (int b = 10; b >= 0; --b) {
      unsigned t = istar | (1u << b);
      int c = 0;
      for (int q = 0; q < nslot; ++q)
        c += (int)__popcll(__ballot(vs[q] == vstar && is_[q] < t));
      if (c <= r - 1) istar = t;
    }
    int base = 0;
    for (int q = 0; q < nslot; ++q) {
      bool sel = (vs[q] < vstar) || (vs[q] == vstar && is_[q] <= istar);
      unsigned long long m = __ballot(sel);
      if (sel) outp[base + mbcnt64(m)] = (int)is_[q];
      base += (int)__popcll(m);
    }
  } else {
    // exact fallback (pathological only): sort-based tournament
    unsigned long long cur = ~0ull;
    for (int s = 0; s < 32; ++s) {
      unsigned idx = (MAP == 0) ? (unsigned)((s >> 2) * 256 + lane * 4 + (s & 3))
                                : (unsigned)((s >> 2) * 256 + (s & 3) * 64 + lane);
      unsigned long long kc = ((unsigned long long)val[s] << 32) | idx;
      cur = lane_merge64(cur, lane_sort64_u64(kc, lane), lane);
    }
    if (lane < KNN) outp[lane] = (int)(unsigned)cur;
  }
}

// --------------------------------- fused knn, EC1 (K=3, exact fp32) ----
// Block: 8 rows (one per wave, 8 waves).  Full feature set (32KB) in LDS.
__global__ __launch_bounds__(512)
void knn3_kernel(const float* __restrict__ xt, const float* __restrict__ sqb,
                 int* __restrict__ idxOut) {
  __shared__ float4 F[2048];                    // 32 KB
  __shared__ float sqS[2048];                   // 8 KB
  __shared__ unsigned long long cbuf[8 * 256];  // 16 KB
  int t = threadIdx.x, lane = t & 63, w = t >> 6;
  long pb = (long)blockIdx.y * Np;
  for (int e = t; e < 2048; e += 512) {
    F[e] = ((const float4*)xt)[pb + e];
    sqS[e] = sqb[pb + e];
  }
  __syncthreads();
  int row = blockIdx.x * 8 + w;
  float4 a = F[row];
  unsigned val[32];
#pragma unroll
  for (int j4 = 0; j4 < 8; ++j4)
#pragma unroll
    for (int u = 0; u < 4; ++u) {
      int col = j4 * 256 + u * 64 + lane;
      float4 fb = F[col];
      float d = sqS[col] - 2.f * (a.x * fb.x + a.y * fb.y + a.z * fb.z);
      unsigned b = __float_as_uint(d);
      val[j4 * 4 + u] = b ^ ((unsigned)((int)b >> 31) | 0x80000000u);
    }
  row_topk<1, 256>(val, cbuf + w * 256, lane, idxOut + (pb + row) * KNN);
}

// --------------------------- fused knn, EC2/3 (K=64, split-bf16 MFMA) ----
// Block: 16 rows, 8 waves.  Wave w: cols [w*256, w*256+256) via 3-term
// split-bf16 MFMA into padded strip Dw[16][2052]; 4-deep register pipeline
// on B loads (R6's 2-deep left waves stalled ~83% — if load latency is the
// stall this recovers it; if flat, residual is L3-BW re-read traffic).
__global__ __launch_bounds__(512)
void knn16_kernel(const __hip_bfloat16* __restrict__ fhi,
                  const __hip_bfloat16* __restrict__ flo,
                  const float* __restrict__ sqb, int* __restrict__ idxOut) {
  constexpr int LDW = 2052;   // pad: stores conflict-free, reads 16B-aligned
  constexpr int CAP = 256;
  __shared__ __align__(16) float Dw[16 * LDW];          // 131,328 B
  __shared__ float sqS[2048];                           // 8 KB
  __shared__ unsigned long long cbuf[8 * CAP];          // 16 KB
  int t = threadIdx.x, lane = t & 63, w = t >> 6;
  long pb = (long)blockIdx.y * Np;
  int r0 = blockIdx.x * 16;
  const __hip_bfloat16* fh = fhi + pb * 64;
  const __hip_bfloat16* fl = flo + pb * 64;

  ((float4*)sqS)[t] = ((const float4*)(sqb + pb))[t];

  // A-frags for the block's 16 rows (K=64, hi/lo)
  int ar = r0 + (lane & 15);
  int kc = (lane >> 4) * 8;
  int n15 = lane & 15;
  bf16x8 ah[2], al[2];
#pragma unroll
  for (int k2 = 0; k2 < 2; ++k2) {
    ah[k2] = *(const bf16x8*)(fh + (long)ar * 64 + k2 * 32 + kc);
    al[k2] = *(const bf16x8*)(fl + (long)ar * 64 + k2 * 32 + kc);
  }
  __syncthreads();

  // phase 1: 16 tiles of 16 cols per wave, 4-slot register pipeline
  int cb0 = w * 256;
  bf16x8 bh[4][2], bl[4][2];
#pragma unroll
  for (int s0 = 0; s0 < 4; ++s0) {
    int bc = cb0 + s0 * 16 + n15;
#pragma unroll
    for (int k2 = 0; k2 < 2; ++k2) {
      bh[s0][k2] = *(const bf16x8*)(fh + (long)bc * 64 + k2 * 32 + kc);
      bl[s0][k2] = *(const bf16x8*)(fl + (long)bc * 64 + k2 * 32 + kc);
    }
  }
  int m0 = (lane >> 4) * 4;
#pragma unroll
  for (int ct = 0; ct < 16; ++ct) {
    const int sl = ct & 3;                 // compile-time (unrolled)
    f32x4 acc = f32x4{0.f, 0.f, 0.f, 0.f};
#pragma unroll
    for (int k2 = 0; k2 < 2; ++k2) {
      acc = __builtin_amdgcn_mfma_f32_16x16x32_bf16(ah[k2], bh[sl][k2], acc, 0, 0, 0);
      acc = __builtin_amdgcn_mfma_f32_16x16x32_bf16(ah[k2], bl[sl][k2], acc, 0, 0, 0);
      acc = __builtin_amdgcn_mfma_f32_16x16x32_bf16(al[k2], bh[sl][k2], acc, 0, 0, 0);
    }
    int col = cb0 + ct * 16 + n15;
    float sqv = sqS[col];
#pragma unroll
    for (int r = 0; r < 4; ++r)
      Dw[(m0 + r) * LDW + col] = sqv - 2.f * acc[r];
    if (ct + 4 < 16) {
      int bc = cb0 + (ct + 4) * 16 + n15;
#pragma unroll
      for (int k2 = 0; k2 < 2; ++k2) {
        bh[sl][k2] = *(const bf16x8*)(fh + (long)bc * 64 + k2 * 32 + kc);
        bl[sl][k2] = *(const bf16x8*)(fl + (long)bc * 64 + k2 * 32 + kc);
      }
    }
  }
  __syncthreads();

  // phase 2: wave w -> local rows w*2, w*2+1
  for (int rr = 0; rr < 2; ++rr) {
    int row = w * 2 + rr;
    unsigned val[32];
    const float4* rp = (const float4*)&Dw[row * LDW];
#pragma unroll
    for (int j4 = 0; j4 < 8; ++j4) {
      float4 f4 = rp[j4 * 64 + lane];
      float fv[4] = {f4.x, f4.y, f4.z, f4.w};
#pragma unroll
      for (int u = 0; u < 4; ++u) {
        unsigned b = __float_as_uint(fv[u]);
        val[j4 * 4 + u] = b ^ ((unsigned)((int)b >> 31) | 0x80000000u);
      }
    }
    row_topk<0, CAP>(val, cbuf + w * CAP, lane, idxOut + (pb + r0 + row) * KNN);
  }
}

// -------------------------------------------------------------- bias ----
template<int CIN, int CP>
__global__ __launch_bounds__(256)
void biasker(const float* __restrict__ feat, const float* __restrict__ w1,
             float* __restrict__ bias) {
  __shared__ float wd[64][CIN + 1];
  int tid = threadIdx.x;
  for (int e = tid; e < 64 * CIN; e += 256) {
    int o = e / CIN, c = e - o * CIN;
    wd[o][c] = w1[o * 2 * CIN + CIN + c] - w1[o * 2 * CIN + c];
  }
  __syncthreads();
  int wv = tid >> 6, o = tid & 63;
  float wr_[CIN];
#pragma unroll
  for (int c = 0; c < CIN; ++c) wr_[c] = wd[o][c];
  long base = (long)blockIdx.y * Np + blockIdx.x * 32 + wv * 8;
  for (int p = 0; p < 8; ++p) {
    const float* fr = feat + (base + p) * CP;
    float acc = 0.f;
#pragma unroll
    for (int c = 0; c < CIN; ++c) acc = fmaf(wr_[c], fr[c], acc);
    bias[(base + p) * 64 + o] = acc;
  }
}

// ------------------------------------------------------ fused edge MFMA ----
template<int K1>   // padded input K: 32 (CIN=3) or 64
__global__ __launch_bounds__(256)
void edge_mfma(const __hip_bfloat16* __restrict__ featb, int fstride,
               const int* __restrict__ idx, const float* __restrict__ bias,
               const __hip_bfloat16* __restrict__ w1b,   // [64][K1] bf16
               const __hip_bfloat16* __restrict__ w2b,   // [64][64] bf16
               const float* __restrict__ bn1, const float* __restrict__ bn2,
               float* __restrict__ fout, __hip_bfloat16* __restrict__ xcseg) {
  __shared__ __align__(16) char lds[32768 + 64 * K1 * 2 + 8192 + 1024 + 512];
  __hip_bfloat16* A  = (__hip_bfloat16*)lds;             // [128][K1]
  __hip_bfloat16* H1 = A + 128 * K1;                     // [128][64]
  float*          H2 = (float*)lds;                      // [128][64] (reuse)
  __hip_bfloat16* W1 = (__hip_bfloat16*)(lds + 32768);   // [64][K1]
  __hip_bfloat16* W2 = W1 + 64 * K1;                     // [64][64]
  float* biasS = (float*)(lds + 32768 + 64 * K1 * 2 + 8192);  // [4][64]
  int*   idxS  = (int*)(biasS + 256);                    // [128]

  int t = threadIdx.x, lane = t & 63, w = t >> 6;
  long pb = (long)blockIdx.y * Np;
  int p0 = blockIdx.x * 4;

  if (t < 128) idxS[t] = idx[(pb + p0 + (t >> 5)) * KNN + (t & 31)];
  biasS[w * 64 + lane] = bias[(pb + p0 + w) * 64 + lane];
  for (int e = t; e < 64 * K1 / 8; e += 256)
    ((ulonglong2*)W1)[e] = ((const ulonglong2*)w1b)[e];
  for (int e = t; e < 512; e += 256)
    ((ulonglong2*)W2)[e] = ((const ulonglong2*)w2b)[e];
  __syncthreads();

  if (K1 == 64) {
#pragma unroll
    for (int i = 0; i < 4; ++i) {
      int e = t + i * 256;              // 1024 chunks of 16B
      int r = e >> 3, cc = e & 7;
      const ulonglong2* src = (const ulonglong2*)(featb + (pb + idxS[r]) * fstride) + cc;
      ((ulonglong2*)(A + r * 64))[cc] = *src;
    }
  } else {
    if (t < 128) {
      int r = t;
      ulonglong2 z; z.x = 0; z.y = 0;
      ((ulonglong2*)(A + r * 32))[0] = *(const ulonglong2*)(featb + (pb + idxS[r]) * fstride);
      ((ulonglong2*)(A + r * 32))[1] = z;
      ((ulonglong2*)(A + r * 32))[2] = z;
      ((ulonglong2*)(A + r * 32))[3] = z;
    }
  }

  int ocol = lane & 15;
  float sc1[4], sh1[4], sc2[4], sh2[4];
#pragma unroll
  for (int jn = 0; jn < 4; ++jn) {
    int o = jn * 16 + ocol;
    sc1[jn] = bn1[o] * rsqrtf(bn1[192 + o] + 1e-5f);
    sh1[jn] = bn1[64 + o] - bn1[128 + o] * sc1[jn];
    sc2[jn] = bn2[o] * rsqrtf(bn2[192 + o] + 1e-5f);
    sh2[jn] = bn2[64 + o] - bn2[128 + o] * sc2[jn];
  }
  __syncthreads();

  int mrow = lane & 15;
  int kc   = (lane >> 4) * 8;
  constexpr int KS = K1 / 32;

  f32x4 acc[2][4];
#pragma unroll
  for (int im = 0; im < 2; ++im)
#pragma unroll
    for (int jn = 0; jn < 4; ++jn) acc[im][jn] = f32x4{0.f, 0.f, 0.f, 0.f};
#pragma unroll
  for (int s = 0; s < KS; ++s) {
    bf16x8 af[2], bf_[4];
#pragma unroll
    for (int im = 0; im < 2; ++im)
      af[im] = *(const bf16x8*)(A + (w * 32 + im * 16 + mrow) * K1 + s * 32 + kc);
#pragma unroll
    for (int jn = 0; jn < 4; ++jn)
      bf_[jn] = *(const bf16x8*)(W1 + (jn * 16 + mrow) * K1 + s * 32 + kc);
#pragma unroll
    for (int im = 0; im < 2; ++im)
#pragma unroll
      for (int jn = 0; jn < 4; ++jn)
        acc[im][jn] = __builtin_amdgcn_mfma_f32_16x16x32_bf16(af[im], bf_[jn], acc[im][jn], 0, 0, 0);
  }
#pragma unroll
  for (int im = 0; im < 2; ++im)
#pragma unroll
    for (int jn = 0; jn < 4; ++jn) {
      int o = jn * 16 + ocol;
      float bsv = biasS[w * 64 + o];
#pragma unroll
      for (int r = 0; r < 4; ++r) {
        int m = w * 32 + im * 16 + (lane >> 4) * 4 + r;
        float x = (acc[im][jn][r] + bsv) * sc1[jn] + sh1[jn];
        x = fmaxf(x, 0.2f * x);
        H1[m * 64 + o] = __float2bfloat16(x);
      }
    }
  __syncthreads();

  bf16x8 a2[2][2], b2[4][2];
#pragma unroll
  for (int im = 0; im < 2; ++im)
#pragma unroll
    for (int s = 0; s < 2; ++s)
      a2[im][s] = *(const bf16x8*)(H1 + (w * 32 + im * 16 + mrow) * 64 + s * 32 + kc);
#pragma unroll
  for (int jn = 0; jn < 4; ++jn)
#pragma unroll
    for (int s = 0; s < 2; ++s)
      b2[jn][s] = *(const bf16x8*)(W2 + (jn * 16 + mrow) * 64 + s * 32 + kc);
  __syncthreads();

  f32x4 acc2[2][4];
#pragma unroll
  for (int im = 0; im < 2; ++im)
#pragma unroll
    for (int jn = 0; jn < 4; ++jn) acc2[im][jn] = f32x4{0.f, 0.f, 0.f, 0.f};
#pragma unroll
  for (int s = 0; s < 2; ++s)
#pragma unroll
    for (int im = 0; im < 2; ++im)
#pragma unroll
      for (int jn = 0; jn < 4; ++jn)
        acc2[im][jn] = __builtin_amdgcn_mfma_f32_16x16x32_bf16(a2[im][s], b2[jn][s], acc2[im][jn], 0, 0, 0);
#pragma unroll
  for (int im = 0; im < 2; ++im)
#pragma unroll
    for (int jn = 0; jn < 4; ++jn) {
      int o = jn * 16 + ocol;
#pragma unroll
      for (int r = 0; r < 4; ++r) {
        int m = w * 32 + im * 16 + (lane >> 4) * 4 + r;
        float x = acc2[im][jn][r] * sc2[jn] + sh2[jn];
        x = fmaxf(x, 0.2f * x);
        H2[m * 64 + o] = x;
      }
    }
  __syncthreads();

  {
    int o = t & 63;
    float m = -3.4e38f;
#pragma unroll
    for (int k = 0; k < 32; ++k) m = fmaxf(m, H2[(w * 32 + k) * 64 + o]);
    int n2 = p0 + w;
    if (fout) fout[(pb + n2) * 64 + o] = m;
    xcseg[(pb + n2) * 192 + o] = __float2bfloat16(m);
  }
}

// --------------------------------------- 256x256 dbuf bf16 TN GEMM ----
// 8 waves (2M x 4N), BK=64, double-buffered LDS (128KB).  4-phase
// interleaved schedule per K-tile (T3-lite + T5): each phase = {8 x
// ds_read_b128, raw s_barrier, setprio(1), 16 MFMA, setprio(0), raw
// s_barrier}.  Memory ordering identical to the 2-phase form: stage-all at
// iteration top, full __syncthreads drain at iteration end (stage latency
// covered by 64 MFMAs).  Raw phase barriers are uniform-control (safe) and
// only create wave role-split for the scheduler; correctness rests solely
// on the __syncthreads fence.  Accumulation order per acc element is
// unchanged (ks0 then ks1) -> bit-identical output.
template<int OUTF, int BNMODE, int RESID, int LRELU>
__global__ __launch_bounds__(512)
void gemm_db(const __hip_bfloat16* __restrict__ A, int lda, long sA,
             const __hip_bfloat16* __restrict__ B, int ldb, long sB,
             void* __restrict__ Cv, int ldc, long sC,
             const __hip_bfloat16* __restrict__ R, long sR,
             const float* __restrict__ bn, int bnlen, int Kd,
             int gx, int gy) {
  int nwg = gx * gy * Bn;           // always % 8 == 0 (Bn = 8)
  int cpx = nwg >> 3;
  int orig = blockIdx.x;
  int wg = (orig & 7) * cpx + (orig >> 3);   // bijective XCD-chunk swizzle
  int bz = wg / (gx * gy);
  int rem = wg - bz * (gx * gy);
  int by = rem / gx;
  int bx = rem - by * gx;
  A += (long)bz * sA;
  B += (long)bz * sB;
  long i0 = (long)bx * 256, j0 = (long)by * 256;

  __shared__ __hip_bfloat16 As[2][256 * 64];
  __shared__ __hip_bfloat16 Bs[2][256 * 64];

  int t = threadIdx.x, lane = t & 63, w = t >> 6;
  int wm = w & 1, wn = w >> 1;      // wave tile: 128(M) x 64(N)

  f32x4 acc[8][4];
#pragma unroll
  for (int im = 0; im < 8; ++im)
#pragma unroll
    for (int jn = 0; jn < 4; ++jn) acc[im][jn] = f32x4{0.f, 0.f, 0.f, 0.f};

#define STAGE_DB(bi, kt)                                                     \
  {                                                                          \
    _Pragma("unroll")                                                        \
    for (int i = 0; i < 4; ++i) {                                            \
      int e = t + i * 512;                                                   \
      int r = e >> 3, c = e & 7;                                             \
      int cs = c ^ (r & 7);                                                  \
      gll16(A + (i0 + r) * lda + (kt) * 64 + cs * 8,                         \
            (__hip_bfloat16*)As[bi] + e * 8);                                \
    }                                                                        \
    _Pragma("unroll")                                                        \
    for (int i = 0; i < 4; ++i) {                                            \
      int e = t + i * 512;                                                   \
      int r = e >> 3, c = e & 7;                                             \
      int cs = c ^ (r & 7);                                                  \
      gll16(B + (j0 + r) * ldb + (kt) * 64 + cs * 8,                         \
            (__hip_bfloat16*)Bs[bi] + e * 8);                                \
    }                                                                        \
  }

  int nt = Kd >> 6;
  STAGE_DB(0, 0);
  __syncthreads();

  int cur = 0;
  for (int kt = 0; kt < nt; ++kt) {
    if (kt + 1 < nt) STAGE_DB(cur ^ 1, kt + 1);
    const __hip_bfloat16* Ab = As[cur];
    const __hip_bfloat16* Bb = Bs[cur];
    bf16x8 bk[4];
#pragma unroll
    for (int p = 0; p < 4; ++p) {
      const int ks = p >> 1, imh = p & 1;
      if (imh == 0) {
#pragma unroll
        for (int jn = 0; jn < 4; ++jn) {
          int rb = wn * 64 + jn * 16 + (lane & 15);
          int q = (ks * 4 + (lane >> 4)) ^ (rb & 7);
          bk[jn] = *(const bf16x8*)(Bb + rb * 64 + q * 8);
        }
      }
      bf16x8 af4[4];
#pragma unroll
      for (int i4 = 0; i4 < 4; ++i4) {
        int im = imh * 4 + i4;
        int ra = wm * 128 + im * 16 + (lane & 15);
        int q = (ks * 4 + (lane >> 4)) ^ (ra & 7);
        af4[i4] = *(const bf16x8*)(Ab + ra * 64 + q * 8);
      }
      __builtin_amdgcn_s_barrier();
      __builtin_amdgcn_s_setprio(1);
#pragma unroll
      for (int i4 = 0; i4 < 4; ++i4)
#pragma unroll
        for (int jn = 0; jn < 4; ++jn)
          acc[imh * 4 + i4][jn] = __builtin_amdgcn_mfma_f32_16x16x32_bf16(
              af4[i4], bk[jn], acc[imh * 4 + i4][jn], 0, 0, 0);
      __builtin_amdgcn_s_setprio(0);
      __builtin_amdgcn_s_barrier();
    }
    __syncthreads();
    cur ^= 1;
  }
#undef STAGE_DB

  int mlocal = (lane >> 4) * 4;
  int nlocal = lane & 15;
#pragma unroll
  for (int i = 0; i < 8; ++i) {
    long m0 = i0 + wm * 128 + i * 16 + mlocal;
    float bsc[4], bsh[4];
    if (BNMODE == 1) {
#pragma unroll
      for (int r = 0; r < 4; ++r) {
        long c = m0 + r;
        float sc = bn[c] * rsqrtf(bn[3 * bnlen + c] + 1e-5f);
        bsc[r] = sc;
        bsh[r] = bn[bnlen + c] - bn[2 * bnlen + c] * sc;
      }
    }
#pragma unroll
    for (int j = 0; j < 4; ++j) {
      long nn = j0 + wn * 64 + j * 16 + nlocal;
      float sc2 = 1.f, sh2 = 0.f;
      if (BNMODE == 2) {
        sc2 = bn[nn] * rsqrtf(bn[3 * bnlen + nn] + 1e-5f);
        sh2 = bn[bnlen + nn] - bn[2 * bnlen + nn] * sc2;
      }
      f32x4 v = acc[i][j];
      float o4[4];
      ushort4 rv;
      if (RESID) rv = *(const ushort4*)(R + (long)bz * sR + nn * ldc + m0);
#pragma unroll
      for (int r = 0; r < 4; ++r) {
        float x = v[r];
        if (RESID) x += bf2f(r == 0 ? rv.x : r == 1 ? rv.y : r == 2 ? rv.z : rv.w);
        if (BNMODE == 1) x = x * bsc[r] + bsh[r];
        if (BNMODE == 2) x = x * sc2 + sh2;
        if (LRELU) x = (x >= 0.f) ? x : 0.2f * x;
        o4[r] = x;
      }
      if (OUTF) {
        float* Cp = (float*)Cv + (long)bz * sC + nn * ldc + m0;
        *(float4*)Cp = make_float4(o4[0], o4[1], o4[2], o4[3]);
      } else {
        __hip_bfloat16* Cp = (__hip_bfloat16*)Cv + (long)bz * sC + nn * ldc + m0;
        ushort4 sv;
        sv.x = f2bf(o4[0]); sv.y = f2bf(o4[1]); sv.z = f2bf(o4[2]); sv.w = f2bf(o4[3]);
        *(ushort4*)Cp = sv;
      }
    }
  }
}

// ----------------------------------------------------------- softmax ----
__global__ __launch_bounds__(256)
void softmax_bf(__hip_bfloat16* __restrict__ S) {
  long row = (long)blockIdx.y * Np + blockIdx.x;
  __hip_bfloat16* p = S + row * Np;
  int t = threadIdx.x;
  const float scale = 0.03125f;  // 1/sqrt(1024)
  float v[8];
  float mx = -3.4e38f;
#pragma unroll
  for (int u = 0; u < 8; ++u) {
    v[u] = __bfloat162float(p[u * 256 + t]) * scale;
    mx = fmaxf(mx, v[u]);
  }
  __shared__ float red[4];
#pragma unroll
  for (int off = 32; off > 0; off >>= 1) mx = fmaxf(mx, __shfl_xor(mx, off));
  if ((t & 63) == 0) red[t >> 6] = mx;
  __syncthreads();
  mx = fmaxf(fmaxf(red[0], red[1]), fmaxf(red[2], red[3]));
  __syncthreads();
  float sum = 0.f;
#pragma unroll
  for (int u = 0; u < 8; ++u) { v[u] = __expf(v[u] - mx); sum += v[u]; }
#pragma unroll
  for (int off = 32; off > 0; off >>= 1) sum += __shfl_xor(sum, off);
  if ((t & 63) == 0) red[t >> 6] = sum;
  __syncthreads();
  sum = red[0] + red[1] + red[2] + red[3];
  float inv = 1.f / sum;
#pragma unroll
  for (int u = 0; u < 8; ++u) p[u * 256 + t] = __float2bfloat16(v[u] * inv);
}

// ------------------------------------------------------------ launch ----
extern "C" void kernel_launch(void* const* d_in, const int* in_sizes, int n_in,
                              void* d_out, int out_size, void* d_ws, size_t ws_size,
                              hipStream_t stream) {
  const float* x       = (const float*)d_in[0];
  const float* ec1_w1  = (const float*)d_in[1];
  const float* ec1_bn1 = (const float*)d_in[2];
  const float* ec1_w2  = (const float*)d_in[3];
  const float* ec1_bn2 = (const float*)d_in[4];
  const float* ec2_w1  = (const float*)d_in[5];
  const float* ec2_bn1 = (const float*)d_in[6];
  const float* ec2_w2  = (const float*)d_in[7];
  const float* ec2_bn2 = (const float*)d_in[8];
  const float* ec3_w1  = (const float*)d_in[9];
  const float* ec3_bn1 = (const float*)d_in[10];
  const float* ec3_w2  = (const float*)d_in[11];
  const float* ec3_bn2 = (const float*)d_in[12];
  const float* emb_w   = (const float*)d_in[13];
  const float* q_w     = (const float*)d_in[14];
  const float* k_w     = (const float*)d_in[15];
  const float* v_w     = (const float*)d_in[16];
  const float* att_bn1 = (const float*)d_in[17];
  const float* ff_w1   = (const float*)d_in[18];
  const float* ff_w2   = (const float*)d_in[19];
  const float* att_bn2 = (const float*)d_in[20];
  const float* cb_w    = (const float*)d_in[21];
  const float* cb_bn   = (const float*)d_in[22];
  float* out = (float*)d_out;
  (void)in_sizes; (void)n_in; (void)out_size; (void)ws_size;

  // ---- workspace layout ----
  float* ws  = (float*)d_ws;
  float* xt  = ws;                        // [B,N,4] fp32       65,536
  float* f1  = xt + 65536;                // [B,N,64] fp32   1,048,576
  float* f2  = f1 + 1048576;              // [B,N,64] fp32   1,048,576
  float* sqb = f2 + 1048576;              // [B,N]              16,384
  int*   idxb = (int*)(sqb + 16384);      // [B,N,32]          524,288
  __hip_bfloat16* xc  = (__hip_bfloat16*)(idxb + 524288);  // [B,N,192] bf16
  __hip_bfloat16* wts = xc + 3145728;     // converted weights, 5,439,488 bf16
  __hip_bfloat16* ew  = wts + 5439488;    // edge weights bf16, 22,528
  __hip_bfloat16* xb  = ew + 22528;       // [B,N,8] bf16, 131,072
  float* big = (float*)(xb + 131072);     // phase A scratch / phase B tensors
  __hip_bfloat16* hb  = (__hip_bfloat16*)big;     // phase B: h   [B,N,1024]
  __hip_bfloat16* qb  = hb + 16777216;            //          q   [B,N,1024]
  __hip_bfloat16* kb  = qb + 16777216;            //          k   [B,N,1024]
  __hip_bfloat16* vtb = kb + 16777216;            //          v^T [B,1024,N]
  __hip_bfloat16* Sb  = vtb + 16777216;           //          S/P [B,N,N] bf16
  __hip_bfloat16* fhi = (__hip_bfloat16*)big;     // phase A: hi [B,N,64] bf16
  __hip_bfloat16* flo = fhi + 1048576;            //          lo [B,N,64] bf16
  float* biasb = big + 33554432;          // [B,N,64] fp32 (phase A only)

  __hip_bfloat16* emb_wb = wts;
  __hip_bfloat16* q_wb   = wts + 196608;
  __hip_bfloat16* k_wb   = wts + 1245184;
  __hip_bfloat16* v_wb   = wts + 2293760;
  __hip_bfloat16* ff1_wb = wts + 3342336;
  __hip_bfloat16* ff2_wb = wts + 3866624;
  __hip_bfloat16* cb_wb  = wts + 4390912;

  __hip_bfloat16* w1a1_b = ew;            // [64][32]  2048
  __hip_bfloat16* w2_1b  = ew + 2048;     // [64][64]  4096
  __hip_bfloat16* w1a2_b = ew + 6144;     // [64][64]  4096
  __hip_bfloat16* w2_2b  = ew + 10240;    // [64][64]  4096
  __hip_bfloat16* w1a3_b = ew + 14336;    // [64][64]  4096
  __hip_bfloat16* w2_3b  = ew + 18432;    // [64][64]  4096

  const long sN1024 = (long)Np * 1024;
  const long sN512  = (long)Np * 512;
  const long sN192  = (long)Np * 192;
  const long sNN    = (long)Np * Np;

  // ---- weight conversion ----
  cvt_bf16_kernel<<<768,  256, 0, stream>>>(emb_w, emb_wb, 196608);
  cvt_bf16_kernel<<<4096, 256, 0, stream>>>(q_w,   q_wb,   1048576);
  cvt_bf16_kernel<<<4096, 256, 0, stream>>>(k_w,   k_wb,   1048576);
  cvt_bf16_kernel<<<4096, 256, 0, stream>>>(v_w,   v_wb,   1048576);
  cvt_bf16_kernel<<<2048, 256, 0, stream>>>(ff_w1, ff1_wb, 524288);
  cvt_bf16_kernel<<<2048, 256, 0, stream>>>(ff_w2, ff2_wb, 524288);
  cvt_bf16_kernel<<<4096, 256, 0, stream>>>(cb_w,  cb_wb,  1048576);
  cvt_w1a<3, 32><<<8, 256, 0, stream>>>(ec1_w1, w1a1_b);
  cvt_w1a<64, 64><<<16, 256, 0, stream>>>(ec2_w1, w1a2_b);
  cvt_w1a<64, 64><<<16, 256, 0, stream>>>(ec3_w1, w1a3_b);
  cvt_bf16_kernel<<<16, 256, 0, stream>>>(ec1_w2, w2_1b, 4096);
  cvt_bf16_kernel<<<16, 256, 0, stream>>>(ec2_w2, w2_2b, 4096);
  cvt_bf16_kernel<<<16, 256, 0, stream>>>(ec3_w2, w2_3b, 4096);

  // ---- transpose input (fp32 [B,N,4] + bf16 [B,N,8]) ----
  xpose_kernel<<<64, 256, 0, stream>>>(x, xt, xb);

  // ---- EdgeConv 1 (exact fp32 fused knn) ----
  sq_kernel<3, 4><<<64, 256, 0, stream>>>(xt, sqb);
  knn3_kernel<<<dim3(Np / 8, Bn), 512, 0, stream>>>(xt, sqb, idxb);
  biasker<3, 4><<<dim3(Np / 32, Bn), 256, 0, stream>>>(xt, ec1_w1, biasb);
  edge_mfma<32><<<dim3(Np / 4, Bn), 256, 0, stream>>>(
      xb, 8, idxb, biasb, w1a1_b, w2_1b, ec1_bn1, ec1_bn2, f1, xc);

  // ---- EdgeConv 2 (split-bf16 MFMA fused knn) ----
  sq_kernel<64, 64><<<64, 256, 0, stream>>>(f1, sqb);
  split_kernel<64, 64><<<4096, 256, 0, stream>>>(f1, fhi, flo);
  knn16_kernel<<<dim3(Np / 16, Bn), 512, 0, stream>>>(fhi, flo, sqb, idxb);
  biasker<64, 64><<<dim3(Np / 32, Bn), 256, 0, stream>>>(f1, ec2_w1, biasb);
  edge_mfma<64><<<dim3(Np / 4, Bn), 256, 0, stream>>>(
      xc, 192, idxb, biasb, w1a2_b, w2_2b, ec2_bn1, ec2_bn2, f2, xc + 64);

  // ---- EdgeConv 3 ----
  sq_kernel<64, 64><<<64, 256, 0, stream>>>(f2, sqb);
  split_kernel<64, 64><<<4096, 256, 0, stream>>>(f2, fhi, flo);
  knn16_kernel<<<dim3(Np / 16, Bn), 512, 0, stream>>>(fhi, flo, sqb, idxb);
  biasker<64, 64><<<dim3(Np / 32, Bn), 256, 0, stream>>>(f2, ec3_w1, biasb);
  edge_mfma<64><<<dim3(Np / 4, Bn), 256, 0, stream>>>(
      xc + 64, 192, idxb, biasb, w1a3_b, w2_3b, ec3_bn1, ec3_bn2, nullptr, xc + 128);

  // ---- emb: h[n][c] = emb_w @ xc (K=192 = 3*64) ----
  gemm_db<0, 0, 0, 0><<<dim3(4 * 8 * Bn), 512, 0, stream>>>(
      emb_wb, 192, 0, xc, 192, sN192, hb, 1024, sN1024, nullptr, 0, nullptr, 0, 192, 4, 8);

  // ---- q, k (as [n][c]), v (as [c][n]) ----
  gemm_db<0, 0, 0, 0><<<dim3(4 * 8 * Bn), 512, 0, stream>>>(
      q_wb, 1024, 0, hb, 1024, sN1024, qb, 1024, sN1024, nullptr, 0, nullptr, 0, 1024, 4, 8);
  gemm_db<0, 0, 0, 0><<<dim3(4 * 8 * Bn), 512, 0, stream>>>(
      k_wb, 1024, 0, hb, 1024, sN1024, kb, 1024, sN1024, nullptr, 0, nullptr, 0, 1024, 4, 8);
  gemm_db<0, 0, 0, 0><<<dim3(8 * 4 * Bn), 512, 0, stream>>>(
      hb, 1024, sN1024, v_wb, 1024, 0, vtb, 2048, sN1024, nullptr, 0, nullptr, 0, 1024, 8, 4);

  // ---- scores S[n][m] = k[m]·q[n], softmax rows ----
  gemm_db<0, 0, 0, 0><<<dim3(8 * 8 * Bn), 512, 0, stream>>>(
      kb, 1024, sN1024, qb, 1024, sN1024, Sb, 2048, sNN, nullptr, 0, nullptr, 0, 1024, 8, 8);
  softmax_bf<<<dim3(Np, Bn), 256, 0, stream>>>(Sb);

  // ---- x_r[n][c] = sum_m P[n][m] vt[c][m]; h = bn1(h + x_r) in place ----
  gemm_db<0, 1, 1, 0><<<dim3(4 * 8 * Bn), 512, 0, stream>>>(
      vtb, 2048, sN1024, Sb, 2048, sNN, hb, 1024, sN1024, hb, sN1024, att_bn1, 1024, 2048, 4, 8);

  // ---- ff1 (lrelu) into qb (M=512 = 2*256) ----
  gemm_db<0, 0, 0, 1><<<dim3(2 * 8 * Bn), 512, 0, stream>>>(
      ff1_wb, 1024, 0, hb, 1024, sN1024, qb, 512, sN512, nullptr, 0, nullptr, 0, 1024, 2, 8);
  // ---- ff2 + resid + bn2, in place on h ----
  gemm_db<0, 1, 1, 0><<<dim3(4 * 8 * Bn), 512, 0, stream>>>(
      ff2_wb, 512, 0, qb, 512, sN512, hb, 1024, sN1024, hb, sN1024, att_bn2, 1024, 512, 4, 8);

  // ---- head: out[o][n] fp32 = lrelu(bn(cb_w @ h)) ----
  gemm_db<1, 2, 0, 1><<<dim3(8 * 4 * Bn), 512, 0, stream>>>(
      hb, 1024, sN1024, cb_wb, 1024, 0, out, 2048, sN1024, nullptr, 0, cb_bn, 1024, 1024, 8, 4);
}

// Round 8
// 943.129 us; speedup vs baseline: 1.0547x; 1.0547x over previous
//
#include <hip/hip_runtime.h>
#include <hip/hip_bf16.h>

constexpr int Bn  = 8;
constexpr int Np  = 2048;
constexpr int KNN = 32;

typedef __attribute__((ext_vector_type(8))) short bf16x8;
typedef __attribute__((ext_vector_type(4))) float f32x4;

__device__ static inline void gll16(const void* g, void* l) {
  __builtin_amdgcn_global_load_lds((const __attribute__((address_space(1))) void*)g,
                                   (__attribute__((address_space(3))) void*)l, 16, 0, 0);
}

__device__ static inline unsigned short f2bf(float x) {
  union { __hip_bfloat16 h; unsigned short u; } cv; cv.h = __float2bfloat16(x); return cv.u;
}
__device__ static inline float bf2f(unsigned short u) {
  union { __hip_bfloat16 h; unsigned short u; } cv; cv.u = u; return __bfloat162float(cv.h);
}

// ------------------------------------------------------------- helpers ----
__global__ __launch_bounds__(256)
void cvt_bf16_kernel(const float* __restrict__ s, __hip_bfloat16* __restrict__ d, int n) {
  int i = blockIdx.x * 256 + threadIdx.x;
  if (i < n) d[i] = __float2bfloat16(s[i]);
}

// W1a (first CIN cols of w1), zero-padded to K1, bf16.
template<int CIN, int K1>
__global__ __launch_bounds__(256)
void cvt_w1a(const float* __restrict__ w1, __hip_bfloat16* __restrict__ out) {
  int i = blockIdx.x * 256 + threadIdx.x;
  if (i >= 64 * K1) return;
  int o = i / K1, c = i - o * K1;
  out[i] = __float2bfloat16(c < CIN ? w1[o * 2 * CIN + c] : 0.f);
}

__global__ __launch_bounds__(256)
void xpose_kernel(const float* __restrict__ x, float* __restrict__ xt,
                  __hip_bfloat16* __restrict__ xb) {
  int i = blockIdx.x * 256 + threadIdx.x;   // over B*N
  int b = i >> 11, n = i & 2047;
  const float* p = x + (long)b * 3 * Np + n;
  float vx = p[0], vy = p[Np], vz = p[2 * Np];
  xt[(long)i * 4 + 0] = vx;
  xt[(long)i * 4 + 1] = vy;
  xt[(long)i * 4 + 2] = vz;
  xt[(long)i * 4 + 3] = 0.f;
  __hip_bfloat16* q = xb + (long)i * 8;
  q[0] = __float2bfloat16(vx); q[1] = __float2bfloat16(vy);
  q[2] = __float2bfloat16(vz);
  q[3] = __float2bfloat16(0.f); q[4] = q[3]; q[5] = q[3]; q[6] = q[3]; q[7] = q[3];
}

template<int C, int CP>
__global__ __launch_bounds__(256)
void sq_kernel(const float* __restrict__ f, float* __restrict__ out) {
  int i = blockIdx.x * 256 + threadIdx.x;   // over B*N
  const float* p = f + (long)i * CP;
  float s = 0.f;
#pragma unroll
  for (int c = 0; c < C; ++c) s += p[c] * p[c];
  out[i] = s;
}

// split fp32 feature -> hi/lo bf16 pair (for fp32-grade MFMA dot products)
template<int CIN, int CP>
__global__ __launch_bounds__(256)
void split_kernel(const float* __restrict__ f, __hip_bfloat16* __restrict__ fhi,
                  __hip_bfloat16* __restrict__ flo) {
  int i = blockIdx.x * 256 + threadIdx.x;   // over B*N*64
  int n = i >> 6, c = i & 63;
  float v = (c < CIN) ? f[(long)n * CP + c] : 0.f;
  __hip_bfloat16 h = __float2bfloat16(v);
  fhi[i] = h;
  flo[i] = __float2bfloat16(v - __bfloat162float(h));
}

// ------------------------------------------------------ topk machinery ----
__device__ static inline unsigned umin32(unsigned a, unsigned b) { return a < b ? a : b; }

__device__ static inline int mbcnt64(unsigned long long m) {
  return __builtin_amdgcn_mbcnt_hi((unsigned)(m >> 32),
         __builtin_amdgcn_mbcnt_lo((unsigned)m, 0u));
}

__device__ static inline unsigned long long shfl64x(unsigned long long k, int m) {
  unsigned lo = (unsigned)__shfl_xor((int)(unsigned)k, m);
  unsigned hi = (unsigned)__shfl_xor((int)(unsigned)(k >> 32), m);
  return ((unsigned long long)hi << 32) | (unsigned long long)lo;
}

// sort-based helpers retained ONLY for the (pathological) S>CAP fallback
__device__ static inline unsigned long long lane_sort64_u64(unsigned long long v, int lane) {
#pragma unroll
  for (int k = 2; k <= 64; k <<= 1) {
#pragma unroll
    for (int j = k >> 1; j > 0; j >>= 1) {
      unsigned long long o = shfl64x(v, j);
      bool dir = ((lane & k) == 0);
      bool lower = ((lane & j) == 0);
      bool keep = (v < o) == (dir == lower);
      v = keep ? v : o;
    }
  }
  return v;
}

__device__ static inline unsigned long long lane_merge64(unsigned long long a,
                                                         unsigned long long b, int lane) {
  unsigned long long br = shfl64x(b, 63);           // reverse of b
  unsigned long long m = a < br ? a : br;           // bitonic, holds lowest 64
#pragma unroll
  for (int j = 32; j > 0; j >>= 1) {
    unsigned long long o = shfl64x(m, j);
    bool lower = ((lane & j) == 0);
    bool keep = (m < o) == lower;
    m = keep ? m : o;
  }
  return m;
}

// k-th smallest (k = km1+1) of the 64 per-lane u32 values v, via bitwise
// binary search on the value domain.  Ballot-only, no DS-pipe shuffles.
__device__ static inline unsigned kth_u32(unsigned v, int km1) {
  unsigned p = 0;
#pragma unroll
  for (int b = 31; b >= 0; --b) {
    unsigned t = p | (1u << b);
    if ((int)__popcll(__ballot(v < t)) <= km1) p = t;
  }
  return p;
}

// Wave-level exact top-32 (by (val,idx) ascending key) of 2048 values held
// as val[32] per lane.  Output UNSORTED (consumer max-pools -> order-free);
// the selected SET is exactly the 32 smallest keys (ties by lowest index).
// MAP 0: idx = (s>>2)*256 + lane*4 + (s&3)   (float4-per-lane fill)
// MAP 1: idx = (s>>2)*256 + (s&3)*64 + lane  (lane-contiguous fill)
template<int MAP, int CAP>
__device__ static inline void row_topk(const unsigned* val, unsigned long long* cbuf,
                                       int lane, int* outp) {
  unsigned tmn[16];
#pragma unroll
  for (int i = 0; i < 16; ++i) tmn[i] = umin32(val[i], val[i + 16]);
#pragma unroll
  for (int w2 = 8; w2 >= 1; w2 >>= 1)
#pragma unroll
    for (int i = 0; i < 8; ++i)
      if (i < w2) tmn[i] = umin32(tmn[i], tmn[i + w2]);

  // T = 32nd smallest of the 64 lane-minima -> exact top-32 all survive v<=T
  unsigned T = kth_u32(tmn[0], 31);

  // ballot-compact survivors into cbuf
  int S = 0;
#pragma unroll
  for (int s = 0; s < 32; ++s) {
    bool p = val[s] <= T;
    unsigned long long mask = __ballot(p);
    int pos = S + mbcnt64(mask);
    unsigned idx = (MAP == 0) ? (unsigned)((s >> 2) * 256 + lane * 4 + (s & 3))
                              : (unsigned)((s >> 2) * 256 + (s & 3) * 64 + lane);
    if (p && pos < CAP) cbuf[pos] = ((unsigned long long)val[s] << 32) | idx;
    S += (int)__popcll(mask);
  }

  if (S <= 64) {
    // hot path: one survivor key per lane
    unsigned long long k = (lane < S) ? cbuf[lane] : ~0ull;
    unsigned vs = (unsigned)(k >> 32), ix = (unsigned)k;
    unsigned vstar = kth_u32(vs, 31);
    int c1 = (int)__popcll(__ballot(vs < vstar));
    int r = 32 - c1;                               // >= 1
    unsigned istar = 0;
#pragma unroll
    for (int b = 10; b >= 0; --b) {
      unsigned t = istar | (1u << b);
      if ((int)__popcll(__ballot(vs == vstar && ix < t)) <= r - 1) istar = t;
    }
    bool sel = (vs < vstar) || (vs == vstar && ix <= istar);
    unsigned long long m = __ballot(sel);
    if (sel) outp[mbcnt64(m)] = (int)ix;
  } else if (S <= CAP) {
    int nslot = (S + 63) >> 6;                     // 2..CAP/64, wave-uniform
    unsigned vs[CAP / 64], is_[CAP / 64];
#pragma unroll
    for (int q = 0; q < CAP / 64; ++q) {
      unsigned long long k = (q * 64 + lane < S) ? cbuf[q * 64 + lane] : ~0ull;
      vs[q] = (unsigned)(k >> 32);
      is_[q] = (unsigned)k;
    }
    unsigned vstar = 0;
#pragma unroll
    for (int b = 31; b >= 0; --b) {
      unsigned t = vstar | (1u << b);
      int c = 0;
      for (int q = 0; q < nslot; ++q) c += (int)__popcll(__ballot(vs[q] < t));
      if (c <= 31) vstar = t;
    }
    int c1 = 0;
    for (int q = 0; q < nslot; ++q) c1 += (int)__popcll(__ballot(vs[q] < vstar));
    int r = 32 - c1;
    unsigned istar = 0;
#pragma unroll
    for (int b = 10; b >= 0; --b) {
      unsigned t = istar | (1u << b);
      int c = 0;
      for (int q = 0; q < nslot; ++q)
        c += (int)__popcll(__ballot(vs[q] == vstar && is_[q] < t));
      if (c <= r - 1) istar = t;
    }
    int base = 0;
    for (int q = 0; q < nslot; ++q) {
      bool sel = (vs[q] < vstar) || (vs[q] == vstar && is_[q] <= istar);
      unsigned long long m = __ballot(sel);
      if (sel) outp[base + mbcnt64(m)] = (int)is_[q];
      base += (int)__popcll(m);
    }
  } else {
    // exact fallback (pathological only): sort-based tournament
    unsigned long long cur = ~0ull;
    for (int s = 0; s < 32; ++s) {
      unsigned idx = (MAP == 0) ? (unsigned)((s >> 2) * 256 + lane * 4 + (s & 3))
                                : (unsigned)((s >> 2) * 256 + (s & 3) * 64 + lane);
      unsigned long long kc = ((unsigned long long)val[s] << 32) | idx;
      cur = lane_merge64(cur, lane_sort64_u64(kc, lane), lane);
    }
    if (lane < KNN) outp[lane] = (int)(unsigned)cur;
  }
}

// --------------------------------- fused knn, EC1 (K=3, exact fp32) ----
// Block: 8 rows (one per wave, 8 waves).  Full feature set (32KB) in LDS.
__global__ __launch_bounds__(512)
void knn3_kernel(const float* __restrict__ xt, const float* __restrict__ sqb,
                 int* __restrict__ idxOut) {
  __shared__ float4 F[2048];                    // 32 KB
  __shared__ float sqS[2048];                   // 8 KB
  __shared__ unsigned long long cbuf[8 * 256];  // 16 KB
  int t = threadIdx.x, lane = t & 63, w = t >> 6;
  long pb = (long)blockIdx.y * Np;
  for (int e = t; e < 2048; e += 512) {
    F[e] = ((const float4*)xt)[pb + e];
    sqS[e] = sqb[pb + e];
  }
  __syncthreads();
  int row = blockIdx.x * 8 + w;
  float4 a = F[row];
  unsigned val[32];
#pragma unroll
  for (int j4 = 0; j4 < 8; ++j4)
#pragma unroll
    for (int u = 0; u < 4; ++u) {
      int col = j4 * 256 + u * 64 + lane;
      float4 fb = F[col];
      float d = sqS[col] - 2.f * (a.x * fb.x + a.y * fb.y + a.z * fb.z);
      unsigned b = __float_as_uint(d);
      val[j4 * 4 + u] = b ^ ((unsigned)((int)b >> 31) | 0x80000000u);
    }
  row_topk<1, 256>(val, cbuf + w * 256, lane, idxOut + (pb + row) * KNN);
}

// --------------------------- fused knn, EC2/3 (K=64, split-bf16 MFMA) ----
// Block: 16 rows, 8 waves.  1-D grid with batch = blockIdx.x & 7 so
// consecutive block IDs (which HW round-robins across the 8 XCDs) belong to
// DIFFERENT batches -> each XCD's L2 serves (mostly) one batch's 512KB
// fhi/flo working set instead of all 8 batches' 4MB (capacity thrash).
// Wave w: cols [w*256, w*256+256) via 3-term split-bf16 MFMA into padded
// strip Dw[16][2052]; 4-deep register pipeline on B loads.
__global__ __launch_bounds__(512)
void knn16_kernel(const __hip_bfloat16* __restrict__ fhi,
                  const __hip_bfloat16* __restrict__ flo,
                  const float* __restrict__ sqb, int* __restrict__ idxOut) {
  constexpr int LDW = 2052;   // pad: stores conflict-free, reads 16B-aligned
  constexpr int CAP = 256;
  __shared__ __align__(16) float Dw[16 * LDW];          // 131,328 B
  __shared__ float sqS[2048];                           // 8 KB
  __shared__ unsigned long long cbuf[8 * CAP];          // 16 KB
  int t = threadIdx.x, lane = t & 63, w = t >> 6;
  int bat = blockIdx.x & 7;           // batch -> XCD pinning
  int tile = blockIdx.x >> 3;
  long pb = (long)bat * Np;
  int r0 = tile * 16;
  const __hip_bfloat16* fh = fhi + pb * 64;
  const __hip_bfloat16* fl = flo + pb * 64;

  ((float4*)sqS)[t] = ((const float4*)(sqb + pb))[t];

  // A-frags for the block's 16 rows (K=64, hi/lo)
  int ar = r0 + (lane & 15);
  int kc = (lane >> 4) * 8;
  int n15 = lane & 15;
  bf16x8 ah[2], al[2];
#pragma unroll
  for (int k2 = 0; k2 < 2; ++k2) {
    ah[k2] = *(const bf16x8*)(fh + (long)ar * 64 + k2 * 32 + kc);
    al[k2] = *(const bf16x8*)(fl + (long)ar * 64 + k2 * 32 + kc);
  }
  __syncthreads();

  // phase 1: 16 tiles of 16 cols per wave, 4-slot register pipeline
  int cb0 = w * 256;
  bf16x8 bh[4][2], bl[4][2];
#pragma unroll
  for (int s0 = 0; s0 < 4; ++s0) {
    int bc = cb0 + s0 * 16 + n15;
#pragma unroll
    for (int k2 = 0; k2 < 2; ++k2) {
      bh[s0][k2] = *(const bf16x8*)(fh + (long)bc * 64 + k2 * 32 + kc);
      bl[s0][k2] = *(const bf16x8*)(fl + (long)bc * 64 + k2 * 32 + kc);
    }
  }
  int m0 = (lane >> 4) * 4;
#pragma unroll
  for (int ct = 0; ct < 16; ++ct) {
    const int sl = ct & 3;                 // compile-time (unrolled)
    f32x4 acc = f32x4{0.f, 0.f, 0.f, 0.f};
#pragma unroll
    for (int k2 = 0; k2 < 2; ++k2) {
      acc = __builtin_amdgcn_mfma_f32_16x16x32_bf16(ah[k2], bh[sl][k2], acc, 0, 0, 0);
      acc = __builtin_amdgcn_mfma_f32_16x16x32_bf16(ah[k2], bl[sl][k2], acc, 0, 0, 0);
      acc = __builtin_amdgcn_mfma_f32_16x16x32_bf16(al[k2], bh[sl][k2], acc, 0, 0, 0);
    }
    int col = cb0 + ct * 16 + n15;
    float sqv = sqS[col];
#pragma unroll
    for (int r = 0; r < 4; ++r)
      Dw[(m0 + r) * LDW + col] = sqv - 2.f * acc[r];
    if (ct + 4 < 16) {
      int bc = cb0 + (ct + 4) * 16 + n15;
#pragma unroll
      for (int k2 = 0; k2 < 2; ++k2) {
        bh[sl][k2] = *(const bf16x8*)(fh + (long)bc * 64 + k2 * 32 + kc);
        bl[sl][k2] = *(const bf16x8*)(fl + (long)bc * 64 + k2 * 32 + kc);
      }
    }
  }
  __syncthreads();

  // phase 2: wave w -> local rows w*2, w*2+1
  for (int rr = 0; rr < 2; ++rr) {
    int row = w * 2 + rr;
    unsigned val[32];
    const float4* rp = (const float4*)&Dw[row * LDW];
#pragma unroll
    for (int j4 = 0; j4 < 8; ++j4) {
      float4 f4 = rp[j4 * 64 + lane];
      float fv[4] = {f4.x, f4.y, f4.z, f4.w};
#pragma unroll
      for (int u = 0; u < 4; ++u) {
        unsigned b = __float_as_uint(fv[u]);
        val[j4 * 4 + u] = b ^ ((unsigned)((int)b >> 31) | 0x80000000u);
      }
    }
    row_topk<0, CAP>(val, cbuf + w * CAP, lane, idxOut + (pb + r0 + row) * KNN);
  }
}

// -------------------------------------------------------------- bias ----
template<int CIN, int CP>
__global__ __launch_bounds__(256)
void biasker(const float* __restrict__ feat, const float* __restrict__ w1,
             float* __restrict__ bias) {
  __shared__ float wd[64][CIN + 1];
  int tid = threadIdx.x;
  for (int e = tid; e < 64 * CIN; e += 256) {
    int o = e / CIN, c = e - o * CIN;
    wd[o][c] = w1[o * 2 * CIN + CIN + c] - w1[o * 2 * CIN + c];
  }
  __syncthreads();
  int wv = tid >> 6, o = tid & 63;
  float wr_[CIN];
#pragma unroll
  for (int c = 0; c < CIN; ++c) wr_[c] = wd[o][c];
  long base = (long)blockIdx.y * Np + blockIdx.x * 32 + wv * 8;
  for (int p = 0; p < 8; ++p) {
    const float* fr = feat + (base + p) * CP;
    float acc = 0.f;
#pragma unroll
    for (int c = 0; c < CIN; ++c) acc = fmaf(wr_[c], fr[c], acc);
    bias[(base + p) * 64 + o] = acc;
  }
}

// ------------------------------------------------------ fused edge MFMA ----
template<int K1>   // padded input K: 32 (CIN=3) or 64
__global__ __launch_bounds__(256)
void edge_mfma(const __hip_bfloat16* __restrict__ featb, int fstride,
               const int* __restrict__ idx, const float* __restrict__ bias,
               const __hip_bfloat16* __restrict__ w1b,   // [64][K1] bf16
               const __hip_bfloat16* __restrict__ w2b,   // [64][64] bf16
               const float* __restrict__ bn1, const float* __restrict__ bn2,
               float* __restrict__ fout, __hip_bfloat16* __restrict__ xcseg) {
  __shared__ __align__(16) char lds[32768 + 64 * K1 * 2 + 8192 + 1024 + 512];
  __hip_bfloat16* A  = (__hip_bfloat16*)lds;             // [128][K1]
  __hip_bfloat16* H1 = A + 128 * K1;                     // [128][64]
  float*          H2 = (float*)lds;                      // [128][64] (reuse)
  __hip_bfloat16* W1 = (__hip_bfloat16*)(lds + 32768);   // [64][K1]
  __hip_bfloat16* W2 = W1 + 64 * K1;                     // [64][64]
  float* biasS = (float*)(lds + 32768 + 64 * K1 * 2 + 8192);  // [4][64]
  int*   idxS  = (int*)(biasS + 256);                    // [128]

  int t = threadIdx.x, lane = t & 63, w = t >> 6;
  long pb = (long)blockIdx.y * Np;
  int p0 = blockIdx.x * 4;

  if (t < 128) idxS[t] = idx[(pb + p0 + (t >> 5)) * KNN + (t & 31)];
  biasS[w * 64 + lane] = bias[(pb + p0 + w) * 64 + lane];
  for (int e = t; e < 64 * K1 / 8; e += 256)
    ((ulonglong2*)W1)[e] = ((const ulonglong2*)w1b)[e];
  for (int e = t; e < 512; e += 256)
    ((ulonglong2*)W2)[e] = ((const ulonglong2*)w2b)[e];
  __syncthreads();

  if (K1 == 64) {
#pragma unroll
    for (int i = 0; i < 4; ++i) {
      int e = t + i * 256;              // 1024 chunks of 16B
      int r = e >> 3, cc = e & 7;
      const ulonglong2* src = (const ulonglong2*)(featb + (pb + idxS[r]) * fstride) + cc;
      ((ulonglong2*)(A + r * 64))[cc] = *src;
    }
  } else {
    if (t < 128) {
      int r = t;
      ulonglong2 z; z.x = 0; z.y = 0;
      ((ulonglong2*)(A + r * 32))[0] = *(const ulonglong2*)(featb + (pb + idxS[r]) * fstride);
      ((ulonglong2*)(A + r * 32))[1] = z;
      ((ulonglong2*)(A + r * 32))[2] = z;
      ((ulonglong2*)(A + r * 32))[3] = z;
    }
  }

  int ocol = lane & 15;
  float sc1[4], sh1[4], sc2[4], sh2[4];
#pragma unroll
  for (int jn = 0; jn < 4; ++jn) {
    int o = jn * 16 + ocol;
    sc1[jn] = bn1[o] * rsqrtf(bn1[192 + o] + 1e-5f);
    sh1[jn] = bn1[64 + o] - bn1[128 + o] * sc1[jn];
    sc2[jn] = bn2[o] * rsqrtf(bn2[192 + o] + 1e-5f);
    sh2[jn] = bn2[64 + o] - bn2[128 + o] * sc2[jn];
  }
  __syncthreads();

  int mrow = lane & 15;
  int kc   = (lane >> 4) * 8;
  constexpr int KS = K1 / 32;

  f32x4 acc[2][4];
#pragma unroll
  for (int im = 0; im < 2; ++im)
#pragma unroll
    for (int jn = 0; jn < 4; ++jn) acc[im][jn] = f32x4{0.f, 0.f, 0.f, 0.f};
#pragma unroll
  for (int s = 0; s < KS; ++s) {
    bf16x8 af[2], bf_[4];
#pragma unroll
    for (int im = 0; im < 2; ++im)
      af[im] = *(const bf16x8*)(A + (w * 32 + im * 16 + mrow) * K1 + s * 32 + kc);
#pragma unroll
    for (int jn = 0; jn < 4; ++jn)
      bf_[jn] = *(const bf16x8*)(W1 + (jn * 16 + mrow) * K1 + s * 32 + kc);
#pragma unroll
    for (int im = 0; im < 2; ++im)
#pragma unroll
      for (int jn = 0; jn < 4; ++jn)
        acc[im][jn] = __builtin_amdgcn_mfma_f32_16x16x32_bf16(af[im], bf_[jn], acc[im][jn], 0, 0, 0);
  }
#pragma unroll
  for (int im = 0; im < 2; ++im)
#pragma unroll
    for (int jn = 0; jn < 4; ++jn) {
      int o = jn * 16 + ocol;
      float bsv = biasS[w * 64 + o];
#pragma unroll
      for (int r = 0; r < 4; ++r) {
        int m = w * 32 + im * 16 + (lane >> 4) * 4 + r;
        float x = (acc[im][jn][r] + bsv) * sc1[jn] + sh1[jn];
        x = fmaxf(x, 0.2f * x);
        H1[m * 64 + o] = __float2bfloat16(x);
      }
    }
  __syncthreads();

  bf16x8 a2[2][2], b2[4][2];
#pragma unroll
  for (int im = 0; im < 2; ++im)
#pragma unroll
    for (int s = 0; s < 2; ++s)
      a2[im][s] = *(const bf16x8*)(H1 + (w * 32 + im * 16 + mrow) * 64 + s * 32 + kc);
#pragma unroll
  for (int jn = 0; jn < 4; ++jn)
#pragma unroll
    for (int s = 0; s < 2; ++s)
      b2[jn][s] = *(const bf16x8*)(W2 + (jn * 16 + mrow) * 64 + s * 32 + kc);
  __syncthreads();

  f32x4 acc2[2][4];
#pragma unroll
  for (int im = 0; im < 2; ++im)
#pragma unroll
    for (int jn = 0; jn < 4; ++jn) acc2[im][jn] = f32x4{0.f, 0.f, 0.f, 0.f};
#pragma unroll
  for (int s = 0; s < 2; ++s)
#pragma unroll
    for (int im = 0; im < 2; ++im)
#pragma unroll
      for (int jn = 0; jn < 4; ++jn)
        acc2[im][jn] = __builtin_amdgcn_mfma_f32_16x16x32_bf16(a2[im][s], b2[jn][s], acc2[im][jn], 0, 0, 0);
#pragma unroll
  for (int im = 0; im < 2; ++im)
#pragma unroll
    for (int jn = 0; jn < 4; ++jn) {
      int o = jn * 16 + ocol;
#pragma unroll
      for (int r = 0; r < 4; ++r) {
        int m = w * 32 + im * 16 + (lane >> 4) * 4 + r;
        float x = acc2[im][jn][r] * sc2[jn] + sh2[jn];
        x = fmaxf(x, 0.2f * x);
        H2[m * 64 + o] = x;
      }
    }
  __syncthreads();

  {
    int o = t & 63;
    float m = -3.4e38f;
#pragma unroll
    for (int k = 0; k < 32; ++k) m = fmaxf(m, H2[(w * 32 + k) * 64 + o]);
    int n2 = p0 + w;
    if (fout) fout[(pb + n2) * 64 + o] = m;
    xcseg[(pb + n2) * 192 + o] = __float2bfloat16(m);
  }
}

// --------------------------------------- 256x256 dbuf bf16 TN GEMM ----
// 8 waves (2M x 4N), BK=64, double-buffered LDS (128KB), ONE barrier per
// K-step (the R6-proven schedule; R7's phase-split barriers regressed).
// XOR-swizzled LDS on both sides; XCD-chunked block swizzle.
template<int OUTF, int BNMODE, int RESID, int LRELU>
__global__ __launch_bounds__(512)
void gemm_db(const __hip_bfloat16* __restrict__ A, int lda, long sA,
             const __hip_bfloat16* __restrict__ B, int ldb, long sB,
             void* __restrict__ Cv, int ldc, long sC,
             const __hip_bfloat16* __restrict__ R, long sR,
             const float* __restrict__ bn, int bnlen, int Kd,
             int gx, int gy) {
  int nwg = gx * gy * Bn;           // always % 8 == 0 (Bn = 8)
  int cpx = nwg >> 3;
  int orig = blockIdx.x;
  int wg = (orig & 7) * cpx + (orig >> 3);   // bijective XCD-chunk swizzle
  int bz = wg / (gx * gy);
  int rem = wg - bz * (gx * gy);
  int by = rem / gx;
  int bx = rem - by * gx;
  A += (long)bz * sA;
  B += (long)bz * sB;
  long i0 = (long)bx * 256, j0 = (long)by * 256;

  __shared__ __hip_bfloat16 As[2][256 * 64];
  __shared__ __hip_bfloat16 Bs[2][256 * 64];

  int t = threadIdx.x, lane = t & 63, w = t >> 6;
  int wm = w & 1, wn = w >> 1;      // wave tile: 128(M) x 64(N)

  f32x4 acc[8][4];
#pragma unroll
  for (int im = 0; im < 8; ++im)
#pragma unroll
    for (int jn = 0; jn < 4; ++jn) acc[im][jn] = f32x4{0.f, 0.f, 0.f, 0.f};

#define STAGE_DB(bi, kt)                                                     \
  {                                                                          \
    _Pragma("unroll")                                                        \
    for (int i = 0; i < 4; ++i) {                                            \
      int e = t + i * 512;                                                   \
      int r = e >> 3, c = e & 7;                                             \
      int cs = c ^ (r & 7);                                                  \
      gll16(A + (i0 + r) * lda + (kt) * 64 + cs * 8,                         \
            (__hip_bfloat16*)As[bi] + e * 8);                                \
    }                                                                        \
    _Pragma("unroll")                                                        \
    for (int i = 0; i < 4; ++i) {                                            \
      int e = t + i * 512;                                                   \
      int r = e >> 3, c = e & 7;                                             \
      int cs = c ^ (r & 7);                                                  \
      gll16(B + (j0 + r) * ldb + (kt) * 64 + cs * 8,                         \
            (__hip_bfloat16*)Bs[bi] + e * 8);                                \
    }                                                                        \
  }

  int nt = Kd >> 6;
  STAGE_DB(0, 0);
  __syncthreads();

  int cur = 0;
  for (int kt = 0; kt < nt; ++kt) {
    if (kt + 1 < nt) STAGE_DB(cur ^ 1, kt + 1);
    const __hip_bfloat16* Ab = As[cur];
    const __hip_bfloat16* Bb = Bs[cur];
#pragma unroll
    for (int ks = 0; ks < 2; ++ks) {
      bf16x8 af[8], bfv[4];
#pragma unroll
      for (int im = 0; im < 8; ++im) {
        int ra = wm * 128 + im * 16 + (lane & 15);
        int q = (ks * 4 + (lane >> 4)) ^ (ra & 7);
        af[im] = *(const bf16x8*)(Ab + ra * 64 + q * 8);
      }
#pragma unroll
      for (int jn = 0; jn < 4; ++jn) {
        int rb = wn * 64 + jn * 16 + (lane & 15);
        int q = (ks * 4 + (lane >> 4)) ^ (rb & 7);
        bfv[jn] = *(const bf16x8*)(Bb + rb * 64 + q * 8);
      }
#pragma unroll
      for (int im = 0; im < 8; ++im)
#pragma unroll
        for (int jn = 0; jn < 4; ++jn)
          acc[im][jn] = __builtin_amdgcn_mfma_f32_16x16x32_bf16(af[im], bfv[jn], acc[im][jn], 0, 0, 0);
    }
    __syncthreads();
    cur ^= 1;
  }
#undef STAGE_DB

  int mlocal = (lane >> 4) * 4;
  int nlocal = lane & 15;
#pragma unroll
  for (int i = 0; i < 8; ++i) {
    long m0 = i0 + wm * 128 + i * 16 + mlocal;
    float bsc[4], bsh[4];
    if (BNMODE == 1) {
#pragma unroll
      for (int r = 0; r < 4; ++r) {
        long c = m0 + r;
        float sc = bn[c] * rsqrtf(bn[3 * bnlen + c] + 1e-5f);
        bsc[r] = sc;
        bsh[r] = bn[bnlen + c] - bn[2 * bnlen + c] * sc;
      }
    }
#pragma unroll
    for (int j = 0; j < 4; ++j) {
      long nn = j0 + wn * 64 + j * 16 + nlocal;
      float sc2 = 1.f, sh2 = 0.f;
      if (BNMODE == 2) {
        sc2 = bn[nn] * rsqrtf(bn[3 * bnlen + nn] + 1e-5f);
        sh2 = bn[bnlen + nn] - bn[2 * bnlen + nn] * sc2;
      }
      f32x4 v = acc[i][j];
      float o4[4];
      ushort4 rv;
      if (RESID) rv = *(const ushort4*)(R + (long)bz * sR + nn * ldc + m0);
#pragma unroll
      for (int r = 0; r < 4; ++r) {
        float x = v[r];
        if (RESID) x += bf2f(r == 0 ? rv.x : r == 1 ? rv.y : r == 2 ? rv.z : rv.w);
        if (BNMODE == 1) x = x * bsc[r] + bsh[r];
        if (BNMODE == 2) x = x * sc2 + sh2;
        if (LRELU) x = (x >= 0.f) ? x : 0.2f * x;
        o4[r] = x;
      }
      if (OUTF) {
        float* Cp = (float*)Cv + (long)bz * sC + nn * ldc + m0;
        *(float4*)Cp = make_float4(o4[0], o4[1], o4[2], o4[3]);
      } else {
        __hip_bfloat16* Cp = (__hip_bfloat16*)Cv + (long)bz * sC + nn * ldc + m0;
        ushort4 sv;
        sv.x = f2bf(o4[0]); sv.y = f2bf(o4[1]); sv.z = f2bf(o4[2]); sv.w = f2bf(o4[3]);
        *(ushort4*)Cp = sv;
      }
    }
  }
}

// ----------------------------------------------------------- softmax ----
__global__ __launch_bounds__(256)
void softmax_bf(__hip_bfloat16* __restrict__ S) {
  long row = (long)blockIdx.y * Np + blockIdx.x;
  __hip_bfloat16* p = S + row * Np;
  int t = threadIdx.x;
  const float scale = 0.03125f;  // 1/sqrt(1024)
  float v[8];
  float mx = -3.4e38f;
#pragma unroll
  for (int u = 0; u < 8; ++u) {
    v[u] = __bfloat162float(p[u * 256 + t]) * scale;
    mx = fmaxf(mx, v[u]);
  }
  __shared__ float red[4];
#pragma unroll
  for (int off = 32; off > 0; off >>= 1) mx = fmaxf(mx, __shfl_xor(mx, off));
  if ((t & 63) == 0) red[t >> 6] = mx;
  __syncthreads();
  mx = fmaxf(fmaxf(red[0], red[1]), fmaxf(red[2], red[3]));
  __syncthreads();
  float sum = 0.f;
#pragma unroll
  for (int u = 0; u < 8; ++u) { v[u] = __expf(v[u] - mx); sum += v[u]; }
#pragma unroll
  for (int off = 32; off > 0; off >>= 1) sum += __shfl_xor(sum, off);
  if ((t & 63) == 0) red[t >> 6] = sum;
  __syncthreads();
  sum = red[0] + red[1] + red[2] + red[3];
  float inv = 1.f / sum;
#pragma unroll
  for (int u = 0; u < 8; ++u) p[u * 256 + t] = __float2bfloat16(v[u] * inv);
}

// ------------------------------------------------------------ launch ----
extern "C" void kernel_launch(void* const* d_in, const int* in_sizes, int n_in,
                              void* d_out, int out_size, void* d_ws, size_t ws_size,
                              hipStream_t stream) {
  const float* x       = (const float*)d_in[0];
  const float* ec1_w1  = (const float*)d_in[1];
  const float* ec1_bn1 = (const float*)d_in[2];
  const float* ec1_w2  = (const float*)d_in[3];
  const float* ec1_bn2 = (const float*)d_in[4];
  const float* ec2_w1  = (const float*)d_in[5];
  const float* ec2_bn1 = (const float*)d_in[6];
  const float* ec2_w2  = (const float*)d_in[7];
  const float* ec2_bn2 = (const float*)d_in[8];
  const float* ec3_w1  = (const float*)d_in[9];
  const float* ec3_bn1 = (const float*)d_in[10];
  const float* ec3_w2  = (const float*)d_in[11];
  const float* ec3_bn2 = (const float*)d_in[12];
  const float* emb_w   = (const float*)d_in[13];
  const float* q_w     = (const float*)d_in[14];
  const float* k_w     = (const float*)d_in[15];
  const float* v_w     = (const float*)d_in[16];
  const float* att_bn1 = (const float*)d_in[17];
  const float* ff_w1   = (const float*)d_in[18];
  const float* ff_w2   = (const float*)d_in[19];
  const float* att_bn2 = (const float*)d_in[20];
  const float* cb_w    = (const float*)d_in[21];
  const float* cb_bn   = (const float*)d_in[22];
  float* out = (float*)d_out;
  (void)in_sizes; (void)n_in; (void)out_size; (void)ws_size;

  // ---- workspace layout ----
  float* ws  = (float*)d_ws;
  float* xt  = ws;                        // [B,N,4] fp32       65,536
  float* f1  = xt + 65536;                // [B,N,64] fp32   1,048,576
  float* f2  = f1 + 1048576;              // [B,N,64] fp32   1,048,576
  float* sqb = f2 + 1048576;              // [B,N]              16,384
  int*   idxb = (int*)(sqb + 16384);      // [B,N,32]          524,288
  __hip_bfloat16* xc  = (__hip_bfloat16*)(idxb + 524288);  // [B,N,192] bf16
  __hip_bfloat16* wts = xc + 3145728;     // converted weights, 5,439,488 bf16
  __hip_bfloat16* ew  = wts + 5439488;    // edge weights bf16, 22,528
  __hip_bfloat16* xb  = ew + 22528;       // [B,N,8] bf16, 131,072
  float* big = (float*)(xb + 131072);     // phase A scratch / phase B tensors
  __hip_bfloat16* hb  = (__hip_bfloat16*)big;     // phase B: h   [B,N,1024]
  __hip_bfloat16* qb  = hb + 16777216;            //          q   [B,N,1024]
  __hip_bfloat16* kb  = qb + 16777216;            //          k   [B,N,1024]
  __hip_bfloat16* vtb = kb + 16777216;            //          v^T [B,1024,N]
  __hip_bfloat16* Sb  = vtb + 16777216;           //          S/P [B,N,N] bf16
  __hip_bfloat16* fhi = (__hip_bfloat16*)big;     // phase A: hi [B,N,64] bf16
  __hip_bfloat16* flo = fhi + 1048576;            //          lo [B,N,64] bf16
  float* biasb = big + 33554432;          // [B,N,64] fp32 (phase A only)

  __hip_bfloat16* emb_wb = wts;
  __hip_bfloat16* q_wb   = wts + 196608;
  __hip_bfloat16* k_wb   = wts + 1245184;
  __hip_bfloat16* v_wb   = wts + 2293760;
  __hip_bfloat16* ff1_wb = wts + 3342336;
  __hip_bfloat16* ff2_wb = wts + 3866624;
  __hip_bfloat16* cb_wb  = wts + 4390912;

  __hip_bfloat16* w1a1_b = ew;            // [64][32]  2048
  __hip_bfloat16* w2_1b  = ew + 2048;     // [64][64]  4096
  __hip_bfloat16* w1a2_b = ew + 6144;     // [64][64]  4096
  __hip_bfloat16* w2_2b  = ew + 10240;    // [64][64]  4096
  __hip_bfloat16* w1a3_b = ew + 14336;    // [64][64]  4096
  __hip_bfloat16* w2_3b  = ew + 18432;    // [64][64]  4096

  const long sN1024 = (long)Np * 1024;
  const long sN512  = (long)Np * 512;
  const long sN192  = (long)Np * 192;
  const long sNN    = (long)Np * Np;

  // ---- weight conversion ----
  cvt_bf16_kernel<<<768,  256, 0, stream>>>(emb_w, emb_wb, 196608);
  cvt_bf16_kernel<<<4096, 256, 0, stream>>>(q_w,   q_wb,   1048576);
  cvt_bf16_kernel<<<4096, 256, 0, stream>>>(k_w,   k_wb,   1048576);
  cvt_bf16_kernel<<<4096, 256, 0, stream>>>(v_w,   v_wb,   1048576);
  cvt_bf16_kernel<<<2048, 256, 0, stream>>>(ff_w1, ff1_wb, 524288);
  cvt_bf16_kernel<<<2048, 256, 0, stream>>>(ff_w2, ff2_wb, 524288);
  cvt_bf16_kernel<<<4096, 256, 0, stream>>>(cb_w,  cb_wb,  1048576);
  cvt_w1a<3, 32><<<8, 256, 0, stream>>>(ec1_w1, w1a1_b);
  cvt_w1a<64, 64><<<16, 256, 0, stream>>>(ec2_w1, w1a2_b);
  cvt_w1a<64, 64><<<16, 256, 0, stream>>>(ec3_w1, w1a3_b);
  cvt_bf16_kernel<<<16, 256, 0, stream>>>(ec1_w2, w2_1b, 4096);
  cvt_bf16_kernel<<<16, 256, 0, stream>>>(ec2_w2, w2_2b, 4096);
  cvt_bf16_kernel<<<16, 256, 0, stream>>>(ec3_w2, w2_3b, 4096);

  // ---- transpose input (fp32 [B,N,4] + bf16 [B,N,8]) ----
  xpose_kernel<<<64, 256, 0, stream>>>(x, xt, xb);

  // ---- EdgeConv 1 (exact fp32 fused knn) ----
  sq_kernel<3, 4><<<64, 256, 0, stream>>>(xt, sqb);
  knn3_kernel<<<dim3(Np / 8, Bn), 512, 0, stream>>>(xt, sqb, idxb);
  biasker<3, 4><<<dim3(Np / 32, Bn), 256, 0, stream>>>(xt, ec1_w1, biasb);
  edge_mfma<32><<<dim3(Np / 4, Bn), 256, 0, stream>>>(
      xb, 8, idxb, biasb, w1a1_b, w2_1b, ec1_bn1, ec1_bn2, f1, xc);

  // ---- EdgeConv 2 (split-bf16 MFMA fused knn) ----
  sq_kernel<64, 64><<<64, 256, 0, stream>>>(f1, sqb);
  split_kernel<64, 64><<<4096, 256, 0, stream>>>(f1, fhi, flo);
  knn16_kernel<<<dim3(Np / 16 * Bn), 512, 0, stream>>>(fhi, flo, sqb, idxb);
  biasker<64, 64><<<dim3(Np / 32, Bn), 256, 0, stream>>>(f1, ec2_w1, biasb);
  edge_mfma<64><<<dim3(Np / 4, Bn), 256, 0, stream>>>(
      xc, 192, idxb, biasb, w1a2_b, w2_2b, ec2_bn1, ec2_bn2, f2, xc + 64);

  // ---- EdgeConv 3 ----
  sq_kernel<64, 64><<<64, 256, 0, stream>>>(f2, sqb);
  split_kernel<64, 64><<<4096, 256, 0, stream>>>(f2, fhi, flo);
  knn16_kernel<<<dim3(Np / 16 * Bn), 512, 0, stream>>>(fhi, flo, sqb, idxb);
  biasker<64, 64><<<dim3(Np / 32, Bn), 256, 0, stream>>>(f2, ec3_w1, biasb);
  edge_mfma<64><<<dim3(Np / 4, Bn), 256, 0, stream>>>(
      xc + 64, 192, idxb, biasb, w1a3_b, w2_3b, ec3_bn1, ec3_bn2, nullptr, xc + 128);

  // ---- emb: h[n][c] = emb_w @ xc (K=192 = 3*64) ----
  gemm_db<0, 0, 0, 0><<<dim3(4 * 8 * Bn), 512, 0, stream>>>(
      emb_wb, 192, 0, xc, 192, sN192, hb, 1024, sN1024, nullptr, 0, nullptr, 0, 192, 4, 8);

  // ---- q, k (as [n][c]), v (as [c][n]) ----
  gemm_db<0, 0, 0, 0><<<dim3(4 * 8 * Bn), 512, 0, stream>>>(
      q_wb, 1024, 0, hb, 1024, sN1024, qb, 1024, sN1024, nullptr, 0, nullptr, 0, 1024, 4, 8);
  gemm_db<0, 0, 0, 0><<<dim3(4 * 8 * Bn), 512, 0, stream>>>(
      k_wb, 1024, 0, hb, 1024, sN1024, kb, 1024, sN1024, nullptr, 0, nullptr, 0, 1024, 4, 8);
  gemm_db<0, 0, 0, 0><<<dim3(8 * 4 * Bn), 512, 0, stream>>>(
      hb, 1024, sN1024, v_wb, 1024, 0, vtb, 2048, sN1024, nullptr, 0, nullptr, 0, 1024, 8, 4);

  // ---- scores S[n][m] = k[m]·q[n], softmax rows ----
  gemm_db<0, 0, 0, 0><<<dim3(8 * 8 * Bn), 512, 0, stream>>>(
      kb, 1024, sN1024, qb, 1024, sN1024, Sb, 2048, sNN, nullptr, 0, nullptr, 0, 1024, 8, 8);
  softmax_bf<<<dim3(Np, Bn), 256, 0, stream>>>(Sb);

  // ---- x_r[n][c] = sum_m P[n][m] vt[c][m]; h = bn1(h + x_r) in place ----
  gemm_db<0, 1, 1, 0><<<dim3(4 * 8 * Bn), 512, 0, stream>>>(
      vtb, 2048, sN1024, Sb, 2048, sNN, hb, 1024, sN1024, hb, sN1024, att_bn1, 1024, 2048, 4, 8);

  // ---- ff1 (lrelu) into qb (M=512 = 2*256) ----
  gemm_db<0, 0, 0, 1><<<dim3(2 * 8 * Bn), 512, 0, stream>>>(
      ff1_wb, 1024, 0, hb, 1024, sN1024, qb, 512, sN512, nullptr, 0, nullptr, 0, 1024, 2, 8);
  // ---- ff2 + resid + bn2, in place on h ----
  gemm_db<0, 1, 1, 0><<<dim3(4 * 8 * Bn), 512, 0, stream>>>(
      ff2_wb, 512, 0, qb, 512, sN512, hb, 1024, sN1024, hb, sN1024, att_bn2, 1024, 512, 4, 8);

  // ---- head: out[o][n] fp32 = lrelu(bn(cb_w @ h)) ----
  gemm_db<1, 2, 0, 1><<<dim3(8 * 4 * Bn), 512, 0, stream>>>(
      hb, 1024, sN1024, cb_wb, 1024, 0, out, 2048, sN1024, nullptr, 0, cb_bn, 1024, 1024, 8, 4);
}